// Round 1
// baseline (78.646 us; speedup 1.0000x reference)
//
#include <hip/hip_runtime.h>

#define BATCH     32768
#define IN_DIM    256
#define N_NEURONS 128
#define DEG1      8                    // MAX_DEGREE+1
#define FEAT      (IN_DIM * DEG1)      // 2048
#define ROWS_PER_WAVE 8

// ---------------------------------------------------------------------------
// Kernel 1: csum[f] = sum_n coeffs[n, f]   (coeffs is [128, 2048] row-major)
// 32 blocks x 256 threads; block handles 64 features, 4 n-groups of 32.
// ---------------------------------------------------------------------------
__global__ __launch_bounds__(256) void reduce_coeffs(const float* __restrict__ coeffs,
                                                     float* __restrict__ csum) {
    __shared__ float part[4][64];
    const int t = threadIdx.x;
    const int f_local = t & 63;
    const int ng = t >> 6;                       // 0..3
    const int f = blockIdx.x * 64 + f_local;     // 32 * 64 = 2048 features
    float s = 0.f;
    const float* p = coeffs + (size_t)(ng * 32) * FEAT + f;
#pragma unroll
    for (int n = 0; n < 32; ++n) s += p[(size_t)n * FEAT];
    part[ng][f_local] = s;
    __syncthreads();
    if (ng == 0) {
        csum[f] = part[0][f_local] + part[1][f_local] + part[2][f_local] + part[3][f_local];
    }
}

// ---------------------------------------------------------------------------
// Kernel 2: out[b] = sum_i sum_d T_d(x[b,i]) * csum[i*8+d]
// One wave (64 lanes) per ROWS_PER_WAVE rows; lane l owns dims 4l..4l+3.
// Coefficients live in registers (32/lane, row-invariant); x loads are one
// coalesced float4 per lane per row.
// ---------------------------------------------------------------------------
__global__ __launch_bounds__(256) void kan_fwd(const float* __restrict__ x,
                                               const float* __restrict__ csum,
                                               float* __restrict__ out) {
    const int lane = threadIdx.x & 63;
    const int wave = threadIdx.x >> 6;                       // 0..3
    const int row0 = (blockIdx.x * 4 + wave) * ROWS_PER_WAVE;

    // Per-lane coefficients for dims 4*lane .. 4*lane+3 (8 degrees each).
    float c[4][8];
    const float4* c4 = (const float4*)csum + (size_t)lane * 8;
#pragma unroll
    for (int j = 0; j < 4; ++j) {
        float4 a = c4[j * 2];
        float4 b = c4[j * 2 + 1];
        c[j][0] = a.x; c[j][1] = a.y; c[j][2] = a.z; c[j][3] = a.w;
        c[j][4] = b.x; c[j][5] = b.y; c[j][6] = b.z; c[j][7] = b.w;
    }

    float acc[ROWS_PER_WAVE];
    const float4* xr = (const float4*)x + (size_t)row0 * (IN_DIM / 4) + lane;

#pragma unroll
    for (int r = 0; r < ROWS_PER_WAVE; ++r) {
        float4 xv = xr[(size_t)r * (IN_DIM / 4)];
        float xs[4] = {xv.x, xv.y, xv.z, xv.w};
        float a = 0.f;
#pragma unroll
        for (int j = 0; j < 4; ++j) {
            const float xx = xs[j];
            const float two_x = xx + xx;
            // T0 = 1, T1 = x
            a = fmaf(c[j][1], xx, a + c[j][0]);
            float tp = 1.f, tc = xx;
#pragma unroll
            for (int d = 2; d < 8; ++d) {
                float tn = fmaf(two_x, tc, -tp);   // T_d = 2x*T_{d-1} - T_{d-2}
                a = fmaf(c[j][d], tn, a);
                tp = tc; tc = tn;
            }
        }
        acc[r] = a;
    }

    // Wave-reduce each row's partial (64 lanes) and store from lane 0.
#pragma unroll
    for (int r = 0; r < ROWS_PER_WAVE; ++r) {
        float a = acc[r];
#pragma unroll
        for (int off = 32; off > 0; off >>= 1) a += __shfl_down(a, off, 64);
        if (lane == 0) out[row0 + r] = a;
    }
}

extern "C" void kernel_launch(void* const* d_in, const int* in_sizes, int n_in,
                              void* d_out, int out_size, void* d_ws, size_t ws_size,
                              hipStream_t stream) {
    const float* x      = (const float*)d_in[0];   // [32768, 256]
    const float* coeffs = (const float*)d_in[1];   // [128, 2048]
    float* out  = (float*)d_out;                   // [32768, 1]
    float* csum = (float*)d_ws;                    // 2048 floats scratch

    reduce_coeffs<<<FEAT / 64, 256, 0, stream>>>(coeffs, csum);
    kan_fwd<<<BATCH / (4 * ROWS_PER_WAVE), 256, 0, stream>>>(x, csum, out);
}

// Round 2
// 77.686 us; speedup vs baseline: 1.0124x; 1.0124x over previous
//
#include <hip/hip_runtime.h>

#define BATCH     32768
#define IN_DIM    256
#define N_NEURONS 128
#define DEG1      8                    // MAX_DEGREE+1
#define FEAT      (IN_DIM * DEG1)      // 2048
#define F4        (FEAT / 4)           // 512 float4 columns
#define XR4       (IN_DIM / 4)         // 64 float4 per x row
#define RPW       16                   // rows per wave

// ---------------------------------------------------------------------------
// Kernel 1: csum[f] = sum_n coeffs[n, f]   (coeffs is [128, 2048] row-major)
// 64 blocks x 256 threads. Block owns 8 float4-columns (32 features).
// Thread (g, c): g = neuron-group of 4, c = float4-col; float4 loads, LDS tree.
// ---------------------------------------------------------------------------
__global__ __launch_bounds__(256) void reduce_coeffs(const float* __restrict__ coeffs,
                                                     float* __restrict__ csum) {
    __shared__ float4 part[256];
    const int t = threadIdx.x;
    const int c = t & 7;                     // 0..7 float4-col within block
    const int g = t >> 3;                    // 0..31 neuron group (4 neurons each)
    const int col4 = blockIdx.x * 8 + c;     // 64 * 8 = 512 float4 columns

    const float4* p = (const float4*)coeffs + (size_t)(g * 4) * F4 + col4;
    float4 s = make_float4(0.f, 0.f, 0.f, 0.f);
#pragma unroll
    for (int n = 0; n < 4; ++n) {
        float4 v = p[(size_t)n * F4];
        s.x += v.x; s.y += v.y; s.z += v.z; s.w += v.w;
    }
    part[t] = s;
    __syncthreads();

    // reduce over g (t = g*8 + c): strides 128,64,32,16,8 -> g offsets 16..1
#pragma unroll
    for (int stride = 128; stride >= 8; stride >>= 1) {
        if (t < stride) {
            float4 o = part[t + stride];
            float4 m = part[t];
            m.x += o.x; m.y += o.y; m.z += o.z; m.w += o.w;
            part[t] = m;
        }
        __syncthreads();
    }
    if (t < 8) ((float4*)csum)[blockIdx.x * 8 + t] = part[t];
}

// ---------------------------------------------------------------------------
// Kernel 2: out[b] = sum_i sum_d T_d(x[b,i]) * csum[i*8+d]
// One wave per RPW rows; lane l owns dims 4l..4l+3 (one coalesced float4
// x-load per row per lane). Per-lane coefficients (32 floats) in registers,
// amortized over 16 rows. Wave shuffle-reduce per row, float4-packed stores.
// ---------------------------------------------------------------------------
__global__ __launch_bounds__(256) void kan_fwd(const float* __restrict__ x,
                                               const float* __restrict__ csum,
                                               float* __restrict__ out) {
    const int lane = threadIdx.x & 63;
    const int wave = threadIdx.x >> 6;                   // 0..3
    const int row0 = (blockIdx.x * 4 + wave) * RPW;      // 512 blocks * 4 * 16 = 32768

    // Per-lane coefficients for dims 4*lane .. 4*lane+3 (8 degrees each).
    float c[4][8];
    const float4* c4 = (const float4*)csum + (size_t)lane * 8;
#pragma unroll
    for (int j = 0; j < 4; ++j) {
        float4 a = c4[j * 2];
        float4 b = c4[j * 2 + 1];
        c[j][0] = a.x; c[j][1] = a.y; c[j][2] = a.z; c[j][3] = a.w;
        c[j][4] = b.x; c[j][5] = b.y; c[j][6] = b.z; c[j][7] = b.w;
    }

    float acc[RPW];
    const float4* xr = (const float4*)x + (size_t)row0 * XR4 + lane;

#pragma unroll
    for (int r = 0; r < RPW; ++r) {
        float4 xv = xr[(size_t)r * XR4];
        float xs[4] = {xv.x, xv.y, xv.z, xv.w};
        float a = 0.f;
#pragma unroll
        for (int j = 0; j < 4; ++j) {
            const float xx = xs[j];
            const float two_x = xx + xx;
            a = fmaf(c[j][1], xx, a + c[j][0]);   // T0=1, T1=x
            float tp = 1.f, tc = xx;
#pragma unroll
            for (int d = 2; d < 8; ++d) {
                float tn = fmaf(two_x, tc, -tp);  // T_d = 2x*T_{d-1} - T_{d-2}
                a = fmaf(c[j][d], tn, a);
                tp = tc; tc = tn;
            }
        }
        acc[r] = a;
    }

    // Wave-reduce each row's partial; pack 4 row-sums into one float4 store.
#pragma unroll
    for (int rq = 0; rq < RPW / 4; ++rq) {
        float s[4];
#pragma unroll
        for (int k = 0; k < 4; ++k) {
            float a = acc[rq * 4 + k];
#pragma unroll
            for (int off = 32; off > 0; off >>= 1) a += __shfl_down(a, off, 64);
            s[k] = a;
        }
        if (lane == 0) {
            ((float4*)out)[row0 / 4 + rq] = make_float4(s[0], s[1], s[2], s[3]);
        }
    }
}

extern "C" void kernel_launch(void* const* d_in, const int* in_sizes, int n_in,
                              void* d_out, int out_size, void* d_ws, size_t ws_size,
                              hipStream_t stream) {
    const float* x      = (const float*)d_in[0];   // [32768, 256]
    const float* coeffs = (const float*)d_in[1];   // [128, 2048]
    float* out  = (float*)d_out;                   // [32768, 1]
    float* csum = (float*)d_ws;                    // 2048 floats scratch

    reduce_coeffs<<<64, 256, 0, stream>>>(coeffs, csum);
    kan_fwd<<<BATCH / (4 * RPW), 256, 0, stream>>>(x, csum, out);
}